// Round 8
// baseline (179.700 us; speedup 1.0000x reference)
//
#include <hip/hip_runtime.h>
#include <hip/hip_bf16.h>

typedef _Float16 f16;
typedef _Float16 f16x4 __attribute__((ext_vector_type(4)));
typedef _Float16 f16x8 __attribute__((ext_vector_type(8)));
typedef float f32x4 __attribute__((ext_vector_type(4)));

#define HH 96
#define WW 96
#define HWs 9216
#define BN_EPS 1e-5f

// ---- workspace layout (byte offsets) ----
#define OFF_ACT1 0u            // [2][9216][128] f16 : value        4,718,592
#define OFF_ACT2 4718592u      // [2][9216][128] f16 : key|query    4,718,592

// ---------------- conv12: fused transpose + stage1 + stage2 (r6, unchanged) ----------------
__global__ __launch_bounds__(256) void conv12(
    const float* __restrict__ x,
    const float* __restrict__ fv_w, const float* __restrict__ fk_w1, const float* __restrict__ fq_w1,
    const float* __restrict__ fk_w2, const float* __restrict__ fq_w2,
    const float* __restrict__ fv_b,
    const float* __restrict__ fk_b1, const float* __restrict__ fk_bn1,
    const float* __restrict__ fq_b1, const float* __restrict__ fq_bn1,
    const float* __restrict__ fk_b2, const float* __restrict__ fk_bn2,
    const float* __restrict__ fq_b2, const float* __restrict__ fq_bn2,
    f16* __restrict__ act1, f16* __restrict__ act2)
{
  __shared__ f16 As[32 * 264];       // 16,896 B  x-tile [px][k], staged once
  __shared__ f16 Bs[2][256 * 40];    // 40,960 B  W1 k-chunk, double-buffered
  __shared__ f16 kqs[2][32 * 72];    // 9,216 B   k1 / q1 (relu'd)
  const int tid = threadIdx.x;
  const int l = tid & 63, w = tid >> 6;
  const int bb = blockIdx.y;
  const int p0 = blockIdx.x * 32;
  const int lrow = l & 15, lk = (l >> 4) * 8;

  const int spx = tid & 31, scg = tid >> 5;
#pragma unroll
  for (int it = 0; it < 8; ++it) {
    int ch = it * 32 + scg * 4;
    f16x4 av;
#pragma unroll
    for (int j = 0; j < 4; j++)
      av[j] = (f16)x[((size_t)bb * 256 + ch + j) * HWs + p0 + spx];
    *(f16x4*)&As[spx * 264 + ch] = av;
  }

  auto stageW = [&](int ks, int bf) {
#pragma unroll
    for (int it = 0; it < 4; it++) {
      int tt = it * 256 + tid;
      int row = tt >> 2, seg = tt & 3;
      const float* srcp;
      if (it < 2)       srcp = fv_w  + (size_t)row * 256;
      else if (it == 2) srcp = fk_w1 + (size_t)(row - 128) * 256;
      else              srcp = fq_w1 + (size_t)(row - 192) * 256;
      float4 u0 = *(const float4*)&srcp[ks * 32 + seg * 8];
      float4 u1 = *(const float4*)&srcp[ks * 32 + seg * 8 + 4];
      f16x8 h = {(f16)u0.x, (f16)u0.y, (f16)u0.z, (f16)u0.w,
                 (f16)u1.x, (f16)u1.y, (f16)u1.z, (f16)u1.w};
      *(f16x8*)&Bs[bf][row * 40 + seg * 8] = h;
    }
  };

  f32x4 acc[2][4];
#pragma unroll
  for (int i = 0; i < 2; i++)
#pragma unroll
    for (int j = 0; j < 4; j++) acc[i][j] = (f32x4){0.f, 0.f, 0.f, 0.f};

  stageW(0, 0);
#pragma unroll 1
  for (int ks = 0; ks < 8; ks++) {
    __syncthreads();
    if (ks < 7) stageW(ks + 1, (ks + 1) & 1);
    f16x8 a[2], b[4];
#pragma unroll
    for (int mi = 0; mi < 2; mi++)
      a[mi] = *(const f16x8*)&As[(mi * 16 + lrow) * 264 + ks * 32 + lk];
#pragma unroll
    for (int nj = 0; nj < 4; nj++)
      b[nj] = *(const f16x8*)&Bs[ks & 1][(w * 64 + nj * 16 + lrow) * 40 + lk];
#pragma unroll
    for (int mi = 0; mi < 2; mi++)
#pragma unroll
      for (int nj = 0; nj < 4; nj++)
        acc[mi][nj] = __builtin_amdgcn_mfma_f32_16x16x32_f16(a[mi], b[nj], acc[mi][nj], 0, 0, 0);
  }

#pragma unroll
  for (int nj = 0; nj < 4; nj++) {
    int cout = w * 64 + nj * 16 + lrow;
    float s, t;
    if (w < 2) { s = 1.0f; t = fv_b[cout]; }
    else {
      int j = nj * 16 + lrow;
      const float* bn = (w == 2) ? fk_bn1 : fq_bn1;
      const float* bs = (w == 2) ? fk_b1 : fq_b1;
      float g = bn[j], be = bn[64 + j], m = bn[128 + j], v = bn[192 + j];
      s = g * rsqrtf(v + BN_EPS); t = (bs[j] - m) * s + be;
    }
#pragma unroll
    for (int mi = 0; mi < 2; mi++)
#pragma unroll
      for (int r = 0; r < 4; r++) {
        int px = mi * 16 + (l >> 4) * 4 + r;
        float v = acc[mi][nj][r] * s + t;
        if (w < 2) {
          act1[((size_t)bb * HWs + p0 + px) * 128 + cout] = (f16)v;
        } else {
          kqs[w - 2][px * 72 + (nj * 16 + lrow)] = (f16)fmaxf(v, 0.f);
        }
      }
  }
  __syncthreads();

  const int sel = w >> 1, half = w & 1;
  const float* W2s = sel ? fq_w2 : fk_w2;
  f32x4 acc2[2][2];
#pragma unroll
  for (int i = 0; i < 2; i++)
#pragma unroll
    for (int j = 0; j < 2; j++) acc2[i][j] = (f32x4){0.f, 0.f, 0.f, 0.f};
#pragma unroll
  for (int ks = 0; ks < 2; ks++) {
    f16x8 a2[2], b2[2];
#pragma unroll
    for (int mi = 0; mi < 2; mi++)
      a2[mi] = *(const f16x8*)&kqs[sel][(mi * 16 + lrow) * 72 + ks * 32 + lk];
#pragma unroll
    for (int nj = 0; nj < 2; nj++) {
      const float* wp = &W2s[(size_t)(half * 32 + nj * 16 + lrow) * 64 + ks * 32 + lk];
      float4 u0 = *(const float4*)&wp[0];
      float4 u1 = *(const float4*)&wp[4];
      b2[nj] = (f16x8){(f16)u0.x, (f16)u0.y, (f16)u0.z, (f16)u0.w,
                       (f16)u1.x, (f16)u1.y, (f16)u1.z, (f16)u1.w};
    }
#pragma unroll
    for (int mi = 0; mi < 2; mi++)
#pragma unroll
      for (int nj = 0; nj < 2; nj++)
        acc2[mi][nj] = __builtin_amdgcn_mfma_f32_16x16x32_f16(a2[mi], b2[nj], acc2[mi][nj], 0, 0, 0);
  }
#pragma unroll
  for (int nj = 0; nj < 2; nj++) {
    int j2 = half * 32 + nj * 16 + lrow;
    int c2 = sel * 64 + j2;
    const float* bn = sel ? fq_bn2 : fk_bn2;
    const float* bs = sel ? fq_b2 : fk_b2;
    float g = bn[j2], be = bn[64 + j2], m = bn[128 + j2], v = bn[192 + j2];
    float s = g * rsqrtf(v + BN_EPS), t = (bs[j2] - m) * s + be;
#pragma unroll
    for (int mi = 0; mi < 2; mi++)
#pragma unroll
      for (int r = 0; r < 4; r++) {
        int px = mi * 16 + (l >> 4) * 4 + r;
        float vv = fmaxf(acc2[mi][nj][r] * s + t, 0.f);
        act2[((size_t)bb * HWs + p0 + px) * 128 + c2] = (f16)vv;
      }
  }
}

// ---------------- attn_final: 8x8 tile, entry-staged Q/K/V0, 2-pass PV, T14 V1 ----------------
// LDS byte map (78,208 total, 2 blocks/CU):
//   [0,9216)       Qs 64x72        | phase2+: Vs1 196x72 at [0,28224)
//   [9216,37440)   Ks 196x72       |
//   [37440,65664)  Vs0 196x72      | phase3+: ctxs 64x136 at [37440,54848)
//   [65664,78208)  Ps  64x49 f32   (persistent)
__global__ __launch_bounds__(256) void attn_final(const f16* __restrict__ act1,
                                                  const f16* __restrict__ act2,
                                                  const float* __restrict__ W_w,
                                                  const float* __restrict__ W_b,
                                                  float* __restrict__ out)
{
  __shared__ __align__(16) char smem[78208];
  f16* Qs   = (f16*)smem;
  f16* Ks   = (f16*)(smem + 9216);
  f16* Vs0  = (f16*)(smem + 37440);
  f16* Vs1  = (f16*)smem;
  f16* ctxs = (f16*)(smem + 37440);
  float* Ps = (float*)(smem + 65664);

  const int tid = threadIdx.x;
  const int l = tid & 63, w = tid >> 6;
  const int bb = blockIdx.z;
  const int x0 = blockIdx.x * 8, y0 = blockIdx.y * 8;
  const f16* a2 = act2 + (size_t)bb * HWs * 128;
  const f16* a1 = act1 + (size_t)bb * HWs * 128;
  const int lrow = l & 15, lk = (l >> 4) * 8;

  // ---- entry stage: Q, K, V0 (independent, one deep pipeline) ----
#pragma unroll
  for (int it = 0; it < 2; it++) {
    int t = it * 256 + tid;
    int q = t >> 3, seg = t & 7;
    int gp = (y0 + (q >> 3)) * WW + x0 + (q & 7);
    *(f16x8*)&Qs[q * 72 + seg * 8] = *(const f16x8*)&a2[(size_t)gp * 128 + 64 + seg * 8];
  }
  for (int t = tid; t < 1568; t += 256) {
    int kk = t >> 3, seg = t & 7;
    int ky = (kk * 4682) >> 16, kx = kk - 14 * ky;
    int gy = y0 - 3 + ky, gx = x0 - 3 + kx;
    f16x8 v = {(f16)0, (f16)0, (f16)0, (f16)0, (f16)0, (f16)0, (f16)0, (f16)0};
    if ((unsigned)gy < (unsigned)HH && (unsigned)gx < (unsigned)WW)
      v = *(const f16x8*)&a2[((size_t)(gy * WW + gx)) * 128 + seg * 8];
    *(f16x8*)&Ks[kk * 72 + seg * 8] = v;
  }
  for (int t = tid; t < 1568; t += 256) {
    int kk = t >> 3, seg = t & 7;
    int ky = (kk * 4682) >> 16, kx = kk - 14 * ky;
    int gy = y0 - 3 + ky, gx = x0 - 3 + kx;
    f16x8 v = {(f16)0, (f16)0, (f16)0, (f16)0, (f16)0, (f16)0, (f16)0, (f16)0};
    if ((unsigned)gy < (unsigned)HH && (unsigned)gx < (unsigned)WW)
      v = *(const f16x8*)&a1[((size_t)(gy * WW + gx)) * 128 + seg * 8];
    *(f16x8*)&Vs0[kk * 72 + seg * 8] = v;
  }
  __syncthreads();

  // ---- QK: wave w -> q-rows 16w..16w+15, 13 col-frags (rows 196-207 masked below) ----
  f32x4 sc[13];
#pragma unroll
  for (int nj = 0; nj < 13; nj++) sc[nj] = (f32x4){0.f, 0.f, 0.f, 0.f};
#pragma unroll
  for (int ks = 0; ks < 2; ks++) {
    f16x8 aq = *(const f16x8*)&Qs[(w * 16 + lrow) * 72 + ks * 32 + lk];
#pragma unroll
    for (int nj = 0; nj < 13; nj++) {
      f16x8 bk = *(const f16x8*)&Ks[(nj * 16 + lrow) * 72 + ks * 32 + lk];
      sc[nj] = __builtin_amdgcn_mfma_f32_16x16x32_f16(aq, bk, sc[nj], 0, 0, 0);
    }
  }
  // mask non-window cols (unconditional overwrite -> garbage in rows >=196 is safe)
  const int r0 = w * 16 + (l >> 4) * 4;
#pragma unroll
  for (int nj = 0; nj < 13; nj++) {
    int c = nj * 16 + lrow;
    int ky = (c * 4682) >> 16, kx = c - 14 * ky;
#pragma unroll
    for (int r = 0; r < 4; r++) {
      int qy = (r0 + r) >> 3, qx = (r0 + r) & 7;
      bool valid = (c < 196) && ((unsigned)(ky - qy) < 7u) && ((unsigned)(kx - qx) < 7u);
      if (!valid) sc[nj][r] = -1e30f;
    }
  }
  // softmax per q-row
  float mx[4], sm[4], inv[4];
#pragma unroll
  for (int r = 0; r < 4; r++) {
    mx[r] = -1e30f;
#pragma unroll
    for (int nj = 0; nj < 13; nj++) mx[r] = fmaxf(mx[r], sc[nj][r]);
  }
#pragma unroll
  for (int off = 1; off < 16; off <<= 1)
#pragma unroll
    for (int r = 0; r < 4; r++) mx[r] = fmaxf(mx[r], __shfl_xor(mx[r], off));
#pragma unroll
  for (int r = 0; r < 4; r++) sm[r] = 0.f;
#pragma unroll
  for (int nj = 0; nj < 13; nj++)
#pragma unroll
    for (int r = 0; r < 4; r++) {
      float e = __expf(sc[nj][r] - mx[r]);
      sc[nj][r] = e; sm[r] += e;
    }
#pragma unroll
  for (int off = 1; off < 16; off <<= 1)
#pragma unroll
    for (int r = 0; r < 4; r++) sm[r] += __shfl_xor(sm[r], off);
#pragma unroll
  for (int r = 0; r < 4; r++) inv[r] = 1.0f / sm[r];
#pragma unroll
  for (int nj = 0; nj < 13; nj++) {
    int c = nj * 16 + lrow;
    int ky = (c * 4682) >> 16, kx = c - 14 * ky;
#pragma unroll
    for (int r = 0; r < 4; r++) {
      int qy = (r0 + r) >> 3, qx = (r0 + r) & 7;
      int dy = ky - qy, dx = kx - qx;
      if (c < 196 && ((unsigned)dy < 7u) && ((unsigned)dx < 7u))
        Ps[(r0 + r) * 49 + dy * 7 + dx] = sc[nj][r] * inv[r];
    }
  }
  __syncthreads();   // Ps ready; Qs/Ks reads done -> Vs1 region free

  // ---- phase: issue V1 loads early, PV pass0, write V1 late ----
  const int q = tid >> 2;
  const int qy = q >> 3, qx = q & 7;
  const int ch0 = (tid & 3) * 16;

  f16x8 vreg[7];
#pragma unroll
  for (int it = 0; it < 7; ++it) {
    int idx = it * 256 + tid;
    f16x8 v = {(f16)0, (f16)0, (f16)0, (f16)0, (f16)0, (f16)0, (f16)0, (f16)0};
    if (idx < 1568) {
      int kk = idx >> 3, seg = idx & 7;
      int ky = (kk * 4682) >> 16, kx = kk - 14 * ky;
      int gy = y0 - 3 + ky, gx = x0 - 3 + kx;
      if ((unsigned)gy < (unsigned)HH && (unsigned)gx < (unsigned)WW)
        v = *(const f16x8*)&a1[((size_t)(gy * WW + gx)) * 128 + 64 + seg * 8];
    }
    vreg[it] = v;
  }

  float acc0[16], acc1[16];
#pragma unroll
  for (int i = 0; i < 16; i++) acc0[i] = 0.f;
#pragma unroll
  for (int dy = 0; dy < 7; dy++)
#pragma unroll
    for (int dx = 0; dx < 7; dx++) {
      float p = Ps[q * 49 + dy * 7 + dx];
      int kk = (qy + dy) * 14 + qx + dx;
      const f16* vp = &Vs0[kk * 72 + ch0];
      f16x8 v0 = *(const f16x8*)&vp[0];
      f16x8 v1 = *(const f16x8*)&vp[8];
#pragma unroll
      for (int j = 0; j < 8; j++) {
        acc0[j] += (float)v0[j] * p;
        acc0[8 + j] += (float)v1[j] * p;
      }
    }
#pragma unroll
  for (int it = 0; it < 7; ++it) {
    int idx = it * 256 + tid;
    if (idx < 1568)
      *(f16x8*)&Vs1[(idx >> 3) * 72 + (idx & 7) * 8] = vreg[it];
  }
  __syncthreads();   // Vs1 ready; Vs0 reads done -> ctxs region free

  // ---- PV pass1 + ctx writes ----
#pragma unroll
  for (int i = 0; i < 16; i++) acc1[i] = 0.f;
#pragma unroll
  for (int dy = 0; dy < 7; dy++)
#pragma unroll
    for (int dx = 0; dx < 7; dx++) {
      float p = Ps[q * 49 + dy * 7 + dx];
      int kk = (qy + dy) * 14 + qx + dx;
      const f16* vp = &Vs1[kk * 72 + ch0];
      f16x8 v0 = *(const f16x8*)&vp[0];
      f16x8 v1 = *(const f16x8*)&vp[8];
#pragma unroll
      for (int j = 0; j < 8; j++) {
        acc1[j] += (float)v0[j] * p;
        acc1[8 + j] += (float)v1[j] * p;
      }
    }
  {
    f16x8 o0, o1, o2, o3;
#pragma unroll
    for (int j = 0; j < 8; j++) {
      o0[j] = (f16)acc0[j];     o1[j] = (f16)acc0[8 + j];
      o2[j] = (f16)acc1[j];     o3[j] = (f16)acc1[8 + j];
    }
    *(f16x8*)&ctxs[q * 136 + ch0]          = o0;
    *(f16x8*)&ctxs[q * 136 + ch0 + 8]      = o1;
    *(f16x8*)&ctxs[q * 136 + 64 + ch0]     = o2;
    *(f16x8*)&ctxs[q * 136 + 64 + ch0 + 8] = o3;
  }
  __syncthreads();

  // ---- final projection: wave w -> couts [64w,64w+64); A = W_w f32 (inline cvt), B = ctx ----
  f32x4 fac[4][4];
#pragma unroll
  for (int i = 0; i < 4; i++)
#pragma unroll
    for (int j = 0; j < 4; j++) fac[i][j] = (f32x4){0.f, 0.f, 0.f, 0.f};
#pragma unroll
  for (int ks = 0; ks < 4; ks++) {
    f16x8 a3[4], b3[4];
#pragma unroll
    for (int mi = 0; mi < 4; mi++) {
      const float* wp = &W_w[(size_t)(w * 64 + mi * 16 + lrow) * 128 + ks * 32 + lk];
      float4 u0 = *(const float4*)&wp[0];
      float4 u1 = *(const float4*)&wp[4];
      a3[mi] = (f16x8){(f16)u0.x, (f16)u0.y, (f16)u0.z, (f16)u0.w,
                       (f16)u1.x, (f16)u1.y, (f16)u1.z, (f16)u1.w};
    }
#pragma unroll
    for (int nj = 0; nj < 4; nj++)
      b3[nj] = *(const f16x8*)&ctxs[(nj * 16 + lrow) * 136 + ks * 32 + lk];
#pragma unroll
    for (int mi = 0; mi < 4; mi++)
#pragma unroll
      for (int nj = 0; nj < 4; nj++)
        fac[mi][nj] = __builtin_amdgcn_mfma_f32_16x16x32_f16(a3[mi], b3[nj], fac[mi][nj], 0, 0, 0);
  }
#pragma unroll
  for (int mi = 0; mi < 4; mi++)
#pragma unroll
    for (int r = 0; r < 4; r++) {
      int cout = w * 64 + mi * 16 + (l >> 4) * 4 + r;
      float bias = W_b[cout];
#pragma unroll
      for (int nj = 0; nj < 4; nj++) {
        int px = nj * 16 + lrow;
        int gp = (y0 + (px >> 3)) * WW + x0 + (px & 7);
        out[((size_t)bb * 256 + cout) * HWs + gp] = fac[mi][nj][r] + bias;
      }
    }
}

extern "C" void kernel_launch(void* const* d_in, const int* in_sizes, int n_in,
                              void* d_out, int out_size, void* d_ws, size_t ws_size,
                              hipStream_t stream) {
  (void)in_sizes; (void)n_in; (void)out_size; (void)ws_size;
  const float* x      = (const float*)d_in[0];
  const float* fk_w1  = (const float*)d_in[1];
  const float* fk_b1  = (const float*)d_in[2];
  const float* fk_bn1 = (const float*)d_in[3];
  const float* fk_w2  = (const float*)d_in[4];
  const float* fk_b2  = (const float*)d_in[5];
  const float* fk_bn2 = (const float*)d_in[6];
  const float* fq_w1  = (const float*)d_in[7];
  const float* fq_b1  = (const float*)d_in[8];
  const float* fq_bn1 = (const float*)d_in[9];
  const float* fq_w2  = (const float*)d_in[10];
  const float* fq_b2  = (const float*)d_in[11];
  const float* fq_bn2 = (const float*)d_in[12];
  const float* fv_w   = (const float*)d_in[13];
  const float* fv_b   = (const float*)d_in[14];
  const float* W_w    = (const float*)d_in[15];
  const float* W_b    = (const float*)d_in[16];
  char* wsb = (char*)d_ws;
  float* out = (float*)d_out;

  f16* act1 = (f16*)(wsb + OFF_ACT1);
  f16* act2 = (f16*)(wsb + OFF_ACT2);

  conv12<<<dim3(288, 2), dim3(256), 0, stream>>>(
      x, fv_w, fk_w1, fq_w1, fk_w2, fq_w2,
      fv_b, fk_b1, fk_bn1, fq_b1, fq_bn1,
      fk_b2, fk_bn2, fq_b2, fq_bn2, act1, act2);

  attn_final<<<dim3(12, 12, 2), dim3(256), 0, stream>>>(act1, act2, W_w, W_b, out);
}

// Round 9
// 152.817 us; speedup vs baseline: 1.1759x; 1.1759x over previous
//
#include <hip/hip_runtime.h>
#include <hip/hip_bf16.h>

typedef _Float16 f16;
typedef _Float16 f16x4 __attribute__((ext_vector_type(4)));
typedef _Float16 f16x8 __attribute__((ext_vector_type(8)));
typedef float f32x4 __attribute__((ext_vector_type(4)));

#define HH 96
#define WW 96
#define HWs 9216
#define BN_EPS 1e-5f

// ---- workspace layout (byte offsets) ----
#define OFF_ACT1 0u            // [2][9216][128] f16 : value        4,718,592
#define OFF_ACT2 4718592u      // [2][9216][128] f16 : key|query    4,718,592

// ---------------- conv12: fused transpose + stage1 + stage2 (r6, unchanged) ----------------
__global__ __launch_bounds__(256) void conv12(
    const float* __restrict__ x,
    const float* __restrict__ fv_w, const float* __restrict__ fk_w1, const float* __restrict__ fq_w1,
    const float* __restrict__ fk_w2, const float* __restrict__ fq_w2,
    const float* __restrict__ fv_b,
    const float* __restrict__ fk_b1, const float* __restrict__ fk_bn1,
    const float* __restrict__ fq_b1, const float* __restrict__ fq_bn1,
    const float* __restrict__ fk_b2, const float* __restrict__ fk_bn2,
    const float* __restrict__ fq_b2, const float* __restrict__ fq_bn2,
    f16* __restrict__ act1, f16* __restrict__ act2)
{
  __shared__ f16 As[32 * 264];       // 16,896 B  x-tile [px][k], staged once
  __shared__ f16 Bs[2][256 * 40];    // 40,960 B  W1 k-chunk, double-buffered
  __shared__ f16 kqs[2][32 * 72];    // 9,216 B   k1 / q1 (relu'd)
  const int tid = threadIdx.x;
  const int l = tid & 63, w = tid >> 6;
  const int bb = blockIdx.y;
  const int p0 = blockIdx.x * 32;
  const int lrow = l & 15, lk = (l >> 4) * 8;

  const int spx = tid & 31, scg = tid >> 5;
#pragma unroll
  for (int it = 0; it < 8; ++it) {
    int ch = it * 32 + scg * 4;
    f16x4 av;
#pragma unroll
    for (int j = 0; j < 4; j++)
      av[j] = (f16)x[((size_t)bb * 256 + ch + j) * HWs + p0 + spx];
    *(f16x4*)&As[spx * 264 + ch] = av;
  }

  auto stageW = [&](int ks, int bf) {
#pragma unroll
    for (int it = 0; it < 4; it++) {
      int tt = it * 256 + tid;
      int row = tt >> 2, seg = tt & 3;
      const float* srcp;
      if (it < 2)       srcp = fv_w  + (size_t)row * 256;
      else if (it == 2) srcp = fk_w1 + (size_t)(row - 128) * 256;
      else              srcp = fq_w1 + (size_t)(row - 192) * 256;
      float4 u0 = *(const float4*)&srcp[ks * 32 + seg * 8];
      float4 u1 = *(const float4*)&srcp[ks * 32 + seg * 8 + 4];
      f16x8 h = {(f16)u0.x, (f16)u0.y, (f16)u0.z, (f16)u0.w,
                 (f16)u1.x, (f16)u1.y, (f16)u1.z, (f16)u1.w};
      *(f16x8*)&Bs[bf][row * 40 + seg * 8] = h;
    }
  };

  f32x4 acc[2][4];
#pragma unroll
  for (int i = 0; i < 2; i++)
#pragma unroll
    for (int j = 0; j < 4; j++) acc[i][j] = (f32x4){0.f, 0.f, 0.f, 0.f};

  stageW(0, 0);
#pragma unroll 1
  for (int ks = 0; ks < 8; ks++) {
    __syncthreads();
    if (ks < 7) stageW(ks + 1, (ks + 1) & 1);
    f16x8 a[2], b[4];
#pragma unroll
    for (int mi = 0; mi < 2; mi++)
      a[mi] = *(const f16x8*)&As[(mi * 16 + lrow) * 264 + ks * 32 + lk];
#pragma unroll
    for (int nj = 0; nj < 4; nj++)
      b[nj] = *(const f16x8*)&Bs[ks & 1][(w * 64 + nj * 16 + lrow) * 40 + lk];
#pragma unroll
    for (int mi = 0; mi < 2; mi++)
#pragma unroll
      for (int nj = 0; nj < 4; nj++)
        acc[mi][nj] = __builtin_amdgcn_mfma_f32_16x16x32_f16(a[mi], b[nj], acc[mi][nj], 0, 0, 0);
  }

#pragma unroll
  for (int nj = 0; nj < 4; nj++) {
    int cout = w * 64 + nj * 16 + lrow;
    float s, t;
    if (w < 2) { s = 1.0f; t = fv_b[cout]; }
    else {
      int j = nj * 16 + lrow;
      const float* bn = (w == 2) ? fk_bn1 : fq_bn1;
      const float* bs = (w == 2) ? fk_b1 : fq_b1;
      float g = bn[j], be = bn[64 + j], m = bn[128 + j], v = bn[192 + j];
      s = g * rsqrtf(v + BN_EPS); t = (bs[j] - m) * s + be;
    }
#pragma unroll
    for (int mi = 0; mi < 2; mi++)
#pragma unroll
      for (int r = 0; r < 4; r++) {
        int px = mi * 16 + (l >> 4) * 4 + r;
        float v = acc[mi][nj][r] * s + t;
        if (w < 2) {
          act1[((size_t)bb * HWs + p0 + px) * 128 + cout] = (f16)v;
        } else {
          kqs[w - 2][px * 72 + (nj * 16 + lrow)] = (f16)fmaxf(v, 0.f);
        }
      }
  }
  __syncthreads();

  const int sel = w >> 1, half = w & 1;
  const float* W2s = sel ? fq_w2 : fk_w2;
  f32x4 acc2[2][2];
#pragma unroll
  for (int i = 0; i < 2; i++)
#pragma unroll
    for (int j = 0; j < 2; j++) acc2[i][j] = (f32x4){0.f, 0.f, 0.f, 0.f};
#pragma unroll
  for (int ks = 0; ks < 2; ks++) {
    f16x8 a2[2], b2[2];
#pragma unroll
    for (int mi = 0; mi < 2; mi++)
      a2[mi] = *(const f16x8*)&kqs[sel][(mi * 16 + lrow) * 72 + ks * 32 + lk];
#pragma unroll
    for (int nj = 0; nj < 2; nj++) {
      const float* wp = &W2s[(size_t)(half * 32 + nj * 16 + lrow) * 64 + ks * 32 + lk];
      float4 u0 = *(const float4*)&wp[0];
      float4 u1 = *(const float4*)&wp[4];
      b2[nj] = (f16x8){(f16)u0.x, (f16)u0.y, (f16)u0.z, (f16)u0.w,
                       (f16)u1.x, (f16)u1.y, (f16)u1.z, (f16)u1.w};
    }
#pragma unroll
    for (int mi = 0; mi < 2; mi++)
#pragma unroll
      for (int nj = 0; nj < 2; nj++)
        acc2[mi][nj] = __builtin_amdgcn_mfma_f32_16x16x32_f16(a2[mi], b2[nj], acc2[mi][nj], 0, 0, 0);
  }
#pragma unroll
  for (int nj = 0; nj < 2; nj++) {
    int j2 = half * 32 + nj * 16 + lrow;
    int c2 = sel * 64 + j2;
    const float* bn = sel ? fq_bn2 : fk_bn2;
    const float* bs = sel ? fq_b2 : fk_b2;
    float g = bn[j2], be = bn[64 + j2], m = bn[128 + j2], v = bn[192 + j2];
    float s = g * rsqrtf(v + BN_EPS), t = (bs[j2] - m) * s + be;
#pragma unroll
    for (int mi = 0; mi < 2; mi++)
#pragma unroll
      for (int r = 0; r < 4; r++) {
        int px = mi * 16 + (l >> 4) * 4 + r;
        float vv = fmaxf(acc2[mi][nj][r] * s + t, 0.f);
        act2[((size_t)bb * HWs + p0 + px) * 128 + c2] = (f16)vv;
      }
  }
}

// ---------------- attn_final: exact round-4 structure (best measured) ----------------
// 8x8 tile, 288 blocks; V staged global->LDS between softmax and PV; ~104 VGPR.
__global__ __launch_bounds__(256) void attn_final(const f16* __restrict__ act1,
                                                  const f16* __restrict__ act2,
                                                  const float* __restrict__ W_w,
                                                  const float* __restrict__ W_b,
                                                  float* __restrict__ out)
{
  __shared__ float Ps[64 * 52];      // 13,312 B
  __shared__ f16 buf[208 * 136];     // 56,576 B: Qs+Ks -> Vs -> ctxs
  const int tid = threadIdx.x;
  const int l = tid & 63, w = tid >> 6;
  const int bb = blockIdx.z;
  const int x0 = blockIdx.x * 8, y0 = blockIdx.y * 8;
  const f16* a2 = act2 + (size_t)bb * HWs * 128;
  const f16* a1 = act1 + (size_t)bb * HWs * 128;
  f16* Qs = buf;
  f16* Ks = buf + 64 * 72;
  const int lrow = l & 15, lk = (l >> 4) * 8;

  // stage Q (act2 ch 64..127)
#pragma unroll
  for (int it = 0; it < 2; it++) {
    int t = it * 256 + tid;
    int q = t >> 3, seg = t & 7;
    int gp = (y0 + (q >> 3)) * WW + x0 + (q & 7);
    *(f16x8*)&Qs[q * 72 + seg * 8] = *(const f16x8*)&a2[(size_t)gp * 128 + 64 + seg * 8];
  }
  // stage K (act2 ch 0..63), 208 halo rows, zero OOB
  for (int t = tid; t < 1664; t += 256) {
    int kk = t >> 3, seg = t & 7;
    int ky = (kk * 4682) >> 16, kx = kk - 14 * ky;
    int gy = y0 - 3 + ky, gx = x0 - 3 + kx;
    f16x8 v = {(f16)0, (f16)0, (f16)0, (f16)0, (f16)0, (f16)0, (f16)0, (f16)0};
    if (kk < 196 && (unsigned)gy < (unsigned)HH && (unsigned)gx < (unsigned)WW)
      v = *(const f16x8*)&a2[((size_t)(gy * WW + gx)) * 128 + seg * 8];
    *(f16x8*)&Ks[kk * 72 + seg * 8] = v;
  }
  __syncthreads();

  // QK: wave w -> q-rows 16w..16w+15, 13 col-frags, K=64
  f32x4 sc[13];
#pragma unroll
  for (int nj = 0; nj < 13; nj++) sc[nj] = (f32x4){0.f, 0.f, 0.f, 0.f};
#pragma unroll
  for (int ks = 0; ks < 2; ks++) {
    f16x8 aq = *(const f16x8*)&Qs[(w * 16 + lrow) * 72 + ks * 32 + lk];
#pragma unroll
    for (int nj = 0; nj < 13; nj++) {
      f16x8 bk = *(const f16x8*)&Ks[(nj * 16 + lrow) * 72 + ks * 32 + lk];
      sc[nj] = __builtin_amdgcn_mfma_f32_16x16x32_f16(aq, bk, sc[nj], 0, 0, 0);
    }
  }
  // mask non-window cols (image-OOB stays 0 via zero-staged K = reference semantics)
  const int r0 = w * 16 + (l >> 4) * 4;
#pragma unroll
  for (int nj = 0; nj < 13; nj++) {
    int c = nj * 16 + lrow;
    int ky = (c * 4682) >> 16, kx = c - 14 * ky;
#pragma unroll
    for (int r = 0; r < 4; r++) {
      int qy = (r0 + r) >> 3, qx = (r0 + r) & 7;
      bool valid = ((unsigned)(ky - qy) < 7u) && ((unsigned)(kx - qx) < 7u);
      if (!valid) sc[nj][r] = -1e30f;
    }
  }
  // softmax per q-row
  float mx[4], sm[4], inv[4];
#pragma unroll
  for (int r = 0; r < 4; r++) {
    mx[r] = -1e30f;
#pragma unroll
    for (int nj = 0; nj < 13; nj++) mx[r] = fmaxf(mx[r], sc[nj][r]);
  }
#pragma unroll
  for (int off = 1; off < 16; off <<= 1)
#pragma unroll
    for (int r = 0; r < 4; r++) mx[r] = fmaxf(mx[r], __shfl_xor(mx[r], off));
#pragma unroll
  for (int r = 0; r < 4; r++) sm[r] = 0.f;
#pragma unroll
  for (int nj = 0; nj < 13; nj++)
#pragma unroll
    for (int r = 0; r < 4; r++) {
      float e = __expf(sc[nj][r] - mx[r]);
      sc[nj][r] = e; sm[r] += e;
    }
#pragma unroll
  for (int off = 1; off < 16; off <<= 1)
#pragma unroll
    for (int r = 0; r < 4; r++) sm[r] += __shfl_xor(sm[r], off);
#pragma unroll
  for (int r = 0; r < 4; r++) inv[r] = 1.0f / sm[r];
#pragma unroll
  for (int nj = 0; nj < 13; nj++) {
    int c = nj * 16 + lrow;
    int ky = (c * 4682) >> 16, kx = c - 14 * ky;
#pragma unroll
    for (int r = 0; r < 4; r++) {
      int qy = (r0 + r) >> 3, qx = (r0 + r) & 7;
      int dy = ky - qy, dx = kx - qx;
      if (((unsigned)dy < 7u) && ((unsigned)dx < 7u))
        Ps[(r0 + r) * 52 + dy * 7 + dx] = sc[nj][r] * inv[r];
    }
  }
  __syncthreads();

  // stage V (act1 ch 0..127)
  f16* Vs = buf;
  for (int t = tid; t < 3328; t += 256) {
    int kk = t >> 4, seg = t & 15;
    int ky = (kk * 4682) >> 16, kx = kk - 14 * ky;
    int gy = y0 - 3 + ky, gx = x0 - 3 + kx;
    f16x8 v = {(f16)0, (f16)0, (f16)0, (f16)0, (f16)0, (f16)0, (f16)0, (f16)0};
    if (kk < 196 && (unsigned)gy < (unsigned)HH && (unsigned)gx < (unsigned)WW)
      v = *(const f16x8*)&a1[((size_t)(gy * WW + gx)) * 128 + seg * 8];
    *(f16x8*)&Vs[kk * 136 + seg * 8] = v;
  }
  __syncthreads();

  // PV (VALU, f32 acc): thread = (pixel q, 32-ch chunk)
  const int q = tid >> 2;
  const int qy = q >> 3, qx = q & 7;
  const int ch0 = (tid & 3) * 32;
  float acc[32];
#pragma unroll
  for (int i = 0; i < 32; i++) acc[i] = 0.f;
#pragma unroll
  for (int dy = 0; dy < 7; dy++)
#pragma unroll
    for (int dx = 0; dx < 7; dx++) {
      float p = Ps[q * 52 + dy * 7 + dx];
      int kk = (qy + dy) * 14 + qx + dx;
      const f16* vp = &Vs[kk * 136 + ch0];
#pragma unroll
      for (int s = 0; s < 4; s++) {
        f16x8 v = *(const f16x8*)&vp[s * 8];
#pragma unroll
        for (int j = 0; j < 8; j++) acc[s * 8 + j] += (float)v[j] * p;
      }
    }
  __syncthreads();   // all PV reads of Vs complete before ctx overwrite

  // ctx -> LDS (reuse buf rows 0..63)
  f16* ctxs = buf;
#pragma unroll
  for (int s = 0; s < 4; s++) {
    f16x8 o;
#pragma unroll
    for (int j = 0; j < 8; j++) o[j] = (f16)acc[s * 8 + j];
    *(f16x8*)&ctxs[q * 136 + ch0 + s * 8] = o;
  }
  __syncthreads();

  // final projection: wave w -> couts [64w,64w+64); A = W_w f32 (inline cvt), B = ctx (LDS)
  f32x4 fac[4][4];
#pragma unroll
  for (int i = 0; i < 4; i++)
#pragma unroll
    for (int j = 0; j < 4; j++) fac[i][j] = (f32x4){0.f, 0.f, 0.f, 0.f};
#pragma unroll
  for (int ks = 0; ks < 4; ks++) {
    f16x8 a3[4], b3[4];
#pragma unroll
    for (int mi = 0; mi < 4; mi++) {
      const float* wp = &W_w[(size_t)(w * 64 + mi * 16 + lrow) * 128 + ks * 32 + lk];
      float4 u0 = *(const float4*)&wp[0];
      float4 u1 = *(const float4*)&wp[4];
      a3[mi] = (f16x8){(f16)u0.x, (f16)u0.y, (f16)u0.z, (f16)u0.w,
                       (f16)u1.x, (f16)u1.y, (f16)u1.z, (f16)u1.w};
    }
#pragma unroll
    for (int nj = 0; nj < 4; nj++)
      b3[nj] = *(const f16x8*)&ctxs[(nj * 16 + lrow) * 136 + ks * 32 + lk];
#pragma unroll
    for (int mi = 0; mi < 4; mi++)
#pragma unroll
      for (int nj = 0; nj < 4; nj++)
        fac[mi][nj] = __builtin_amdgcn_mfma_f32_16x16x32_f16(a3[mi], b3[nj], fac[mi][nj], 0, 0, 0);
  }
#pragma unroll
  for (int mi = 0; mi < 4; mi++)
#pragma unroll
    for (int r = 0; r < 4; r++) {
      int cout = w * 64 + mi * 16 + (l >> 4) * 4 + r;
      float bias = W_b[cout];
#pragma unroll
      for (int nj = 0; nj < 4; nj++) {
        int px = nj * 16 + lrow;
        int gp = (y0 + (px >> 3)) * WW + x0 + (px & 7);
        out[((size_t)bb * 256 + cout) * HWs + gp] = fac[mi][nj][r] + bias;
      }
    }
}

extern "C" void kernel_launch(void* const* d_in, const int* in_sizes, int n_in,
                              void* d_out, int out_size, void* d_ws, size_t ws_size,
                              hipStream_t stream) {
  (void)in_sizes; (void)n_in; (void)out_size; (void)ws_size;
  const float* x      = (const float*)d_in[0];
  const float* fk_w1  = (const float*)d_in[1];
  const float* fk_b1  = (const float*)d_in[2];
  const float* fk_bn1 = (const float*)d_in[3];
  const float* fk_w2  = (const float*)d_in[4];
  const float* fk_b2  = (const float*)d_in[5];
  const float* fk_bn2 = (const float*)d_in[6];
  const float* fq_w1  = (const float*)d_in[7];
  const float* fq_b1  = (const float*)d_in[8];
  const float* fq_bn1 = (const float*)d_in[9];
  const float* fq_w2  = (const float*)d_in[10];
  const float* fq_b2  = (const float*)d_in[11];
  const float* fq_bn2 = (const float*)d_in[12];
  const float* fv_w   = (const float*)d_in[13];
  const float* fv_b   = (const float*)d_in[14];
  const float* W_w    = (const float*)d_in[15];
  const float* W_b    = (const float*)d_in[16];
  char* wsb = (char*)d_ws;
  float* out = (float*)d_out;

  f16* act1 = (f16*)(wsb + OFF_ACT1);
  f16* act2 = (f16*)(wsb + OFF_ACT2);

  conv12<<<dim3(288, 2), dim3(256), 0, stream>>>(
      x, fv_w, fk_w1, fq_w1, fk_w2, fq_w2,
      fv_b, fk_b1, fk_bn1, fq_b1, fq_bn1,
      fk_b2, fk_bn2, fq_b2, fq_bn2, act1, act2);

  attn_final<<<dim3(12, 12, 2), dim3(256), 0, stream>>>(act1, act2, W_w, W_b, out);
}

// Round 10
// 139.071 us; speedup vs baseline: 1.2921x; 1.0988x over previous
//
#include <hip/hip_runtime.h>
#include <hip/hip_bf16.h>

typedef _Float16 f16;
typedef _Float16 f16x4 __attribute__((ext_vector_type(4)));
typedef _Float16 f16x8 __attribute__((ext_vector_type(8)));
typedef float f32x4 __attribute__((ext_vector_type(4)));

#define HH 96
#define WW 96
#define HWs 9216
#define BN_EPS 1e-5f

// ---- workspace layout (byte offsets) ----
#define OFF_ACT1 0u            // [2][9216][128] f16 : value        4,718,592
#define OFF_ACT2 4718592u      // [2][9216][128] f16 : key|query    4,718,592
#define OFF_W1   9437184u      // [256][256] f16 (value|k1|q1 weights)
#define OFF_W2   9568256u      // [128][64]  f16 (key|query weights)
#define OFF_W3   9584640u      // [256][128] f16
#define OFF_ST   9650176u      // f32: s1[256] t1[256] s2[128] t2[128] t3[256]

// ---------------- prep: fold BN, cast weights to f16 ----------------
__global__ __launch_bounds__(256) void prep_kernel(
    const float* __restrict__ fk_w1, const float* __restrict__ fk_b1, const float* __restrict__ fk_bn1,
    const float* __restrict__ fk_w2, const float* __restrict__ fk_b2, const float* __restrict__ fk_bn2,
    const float* __restrict__ fq_w1, const float* __restrict__ fq_b1, const float* __restrict__ fq_bn1,
    const float* __restrict__ fq_w2, const float* __restrict__ fq_b2, const float* __restrict__ fq_bn2,
    const float* __restrict__ fv_w,  const float* __restrict__ fv_b,
    const float* __restrict__ W_w,   const float* __restrict__ W_b,
    char* __restrict__ wsb)
{
  f16* w1 = (f16*)(wsb + OFF_W1);
  f16* w2 = (f16*)(wsb + OFF_W2);
  f16* w3 = (f16*)(wsb + OFF_W3);
  float* st = (float*)(wsb + OFF_ST);
  int i = blockIdx.x * 256 + threadIdx.x;
  if (i < 65536) {
    int o = i >> 8, c = i & 255;
    float v;
    if (o < 128)      v = fv_w[o * 256 + c];
    else if (o < 192) v = fk_w1[(o - 128) * 256 + c];
    else              v = fq_w1[(o - 192) * 256 + c];
    w1[i] = (f16)v;
  } else if (i < 73728) {
    int j = i - 65536; int o = j >> 6, c = j & 63;
    w2[j] = (f16)((o < 64) ? fk_w2[o * 64 + c] : fq_w2[(o - 64) * 64 + c]);
  } else if (i < 106496) {
    int j = i - 73728;
    w3[j] = (f16)W_w[j];
  } else if (i < 106752) {
    int o = i - 106496;
    float s, t;
    if (o < 128) { s = 1.0f; t = fv_b[o]; }
    else if (o < 192) {
      int j = o - 128;
      float g = fk_bn1[j], be = fk_bn1[64 + j], m = fk_bn1[128 + j], v = fk_bn1[192 + j];
      s = g * rsqrtf(v + BN_EPS); t = (fk_b1[j] - m) * s + be;
    } else {
      int j = o - 192;
      float g = fq_bn1[j], be = fq_bn1[64 + j], m = fq_bn1[128 + j], v = fq_bn1[192 + j];
      s = g * rsqrtf(v + BN_EPS); t = (fq_b1[j] - m) * s + be;
    }
    st[o] = s; st[256 + o] = t;
  } else if (i < 106880) {
    int o = i - 106752;
    float s, t;
    if (o < 64) {
      float g = fk_bn2[o], be = fk_bn2[64 + o], m = fk_bn2[128 + o], v = fk_bn2[192 + o];
      s = g * rsqrtf(v + BN_EPS); t = (fk_b2[o] - m) * s + be;
    } else {
      int j = o - 64;
      float g = fq_bn2[j], be = fq_bn2[64 + j], m = fq_bn2[128 + j], v = fq_bn2[192 + j];
      s = g * rsqrtf(v + BN_EPS); t = (fq_b2[j] - m) * s + be;
    }
    st[512 + o] = s; st[640 + o] = t;
  } else if (i < 107136) {
    int o = i - 106880;
    st[768 + o] = W_b[o];
  }
}

// ---------------- conv12: fused transpose + stage1 (256 couts) + stage2 (in-LDS k1/q1) ----------------
// 32-px tile, 4 waves. Wave w owns stage-1 couts [64w, 64w+64):
//   w=0,1 -> value -> act1 global; w=2 -> k1 -> LDS; w=3 -> q1 -> LDS.
// Then stage2: wave w -> (sel = w>>1 ? query : key), couts2 (w&1)*32..+32, from LDS k1/q1.
__global__ __launch_bounds__(256) void conv12(
    const float* __restrict__ x, const f16* __restrict__ W1, const f16* __restrict__ W2,
    f16* __restrict__ act1, f16* __restrict__ act2, const float* __restrict__ st)
{
  __shared__ f16 As[32 * 40];        // 2,560 B  x-tile transposed [px][k]
  __shared__ f16 Bs[256 * 40];       // 20,480 B W1 k-slice
  __shared__ f16 kqs[2][32 * 72];    // 9,216 B  k1 / q1 (relu'd)
  const int tid = threadIdx.x;
  const int l = tid & 63, w = tid >> 6;
  const int bb = blockIdx.y;
  const int p0 = blockIdx.x * 32;
  const int lrow = l & 15, lk = (l >> 4) * 8;

  f32x4 acc[2][4];
#pragma unroll
  for (int i = 0; i < 2; i++)
#pragma unroll
    for (int j = 0; j < 4; j++) acc[i][j] = (f32x4){0.f, 0.f, 0.f, 0.f};

  const int spx = tid & 31, skg = tid >> 5;   // staging: px, k-quad
#pragma unroll 1
  for (int ks = 0; ks < 8; ks++) {
    // stage A: x NCHW f32 -> As[px][k] f16 (4 strided coalesced loads -> 1 b64 write)
    f16x4 av;
#pragma unroll
    for (int j = 0; j < 4; j++)
      av[j] = (f16)x[((size_t)bb * 256 + ks * 32 + skg * 4 + j) * HWs + p0 + spx];
    *(f16x4*)&As[spx * 40 + skg * 4] = av;
    // stage B: W1 rows 0..255, k-chunk
#pragma unroll
    for (int it = 0; it < 4; it++) {
      int tt = it * 256 + tid;
      int row = tt >> 2, seg = tt & 3;
      *(f16x8*)&Bs[row * 40 + seg * 8] =
          *(const f16x8*)&W1[(size_t)row * 256 + ks * 32 + seg * 8];
    }
    __syncthreads();
    f16x8 a[2], b[4];
#pragma unroll
    for (int mi = 0; mi < 2; mi++) a[mi] = *(const f16x8*)&As[(mi * 16 + lrow) * 40 + lk];
#pragma unroll
    for (int nj = 0; nj < 4; nj++) b[nj] = *(const f16x8*)&Bs[(w * 64 + nj * 16 + lrow) * 40 + lk];
#pragma unroll
    for (int mi = 0; mi < 2; mi++)
#pragma unroll
      for (int nj = 0; nj < 4; nj++)
        acc[mi][nj] = __builtin_amdgcn_mfma_f32_16x16x32_f16(a[mi], b[nj], acc[mi][nj], 0, 0, 0);
    __syncthreads();
  }

  // stage-1 epilogue
#pragma unroll
  for (int mi = 0; mi < 2; mi++)
#pragma unroll
    for (int nj = 0; nj < 4; nj++) {
      int cout = w * 64 + nj * 16 + lrow;
      float s = st[cout], t = st[256 + cout];
#pragma unroll
      for (int r = 0; r < 4; r++) {
        int px = mi * 16 + (l >> 4) * 4 + r;
        float v = acc[mi][nj][r] * s + t;
        if (w < 2) {
          act1[((size_t)bb * HWs + p0 + px) * 128 + cout] = (f16)v;
        } else {
          kqs[w - 2][px * 72 + (nj * 16 + lrow)] = (f16)fmaxf(v, 0.f);
        }
      }
    }
  __syncthreads();

  // stage2: K=64 from LDS k1/q1
  const int sel = w >> 1, half = w & 1;
  const f16* W2s = W2 + sel * 64 * 64;
  f32x4 acc2[2][2];
#pragma unroll
  for (int i = 0; i < 2; i++)
#pragma unroll
    for (int j = 0; j < 2; j++) acc2[i][j] = (f32x4){0.f, 0.f, 0.f, 0.f};
#pragma unroll
  for (int ks = 0; ks < 2; ks++) {
    f16x8 a2[2], b2[2];
#pragma unroll
    for (int mi = 0; mi < 2; mi++)
      a2[mi] = *(const f16x8*)&kqs[sel][(mi * 16 + lrow) * 72 + ks * 32 + lk];
#pragma unroll
    for (int nj = 0; nj < 2; nj++)
      b2[nj] = *(const f16x8*)&W2s[(size_t)(half * 32 + nj * 16 + lrow) * 64 + ks * 32 + lk];
#pragma unroll
    for (int mi = 0; mi < 2; mi++)
#pragma unroll
      for (int nj = 0; nj < 2; nj++)
        acc2[mi][nj] = __builtin_amdgcn_mfma_f32_16x16x32_f16(a2[mi], b2[nj], acc2[mi][nj], 0, 0, 0);
  }
#pragma unroll
  for (int mi = 0; mi < 2; mi++)
#pragma unroll
    for (int nj = 0; nj < 2; nj++) {
      int c2 = sel * 64 + half * 32 + nj * 16 + lrow;   // 0..127 in act2
      float s = st[512 + c2], t = st[640 + c2];
#pragma unroll
      for (int r = 0; r < 4; r++) {
        int px = mi * 16 + (l >> 4) * 4 + r;
        float v = fmaxf(acc2[mi][nj][r] * s + t, 0.f);
        act2[((size_t)bb * HWs + p0 + px) * 128 + c2] = (f16)v;
      }
    }
}

// ---------------- attn_final: 8x8 tile attention + fused output projection ----------------
__global__ __launch_bounds__(256) void attn_final(const f16* __restrict__ act1,
                                                  const f16* __restrict__ act2,
                                                  const f16* __restrict__ W3,
                                                  const float* __restrict__ st,
                                                  float* __restrict__ out)
{
  __shared__ float Ps[64 * 52];      // 13,312 B
  __shared__ f16 buf[208 * 136];     // 56,576 B: Qs+Ks -> Vs -> ctxs
  const int tid = threadIdx.x;
  const int l = tid & 63, w = tid >> 6;
  const int bb = blockIdx.z;
  const int x0 = blockIdx.x * 8, y0 = blockIdx.y * 8;
  const f16* a2 = act2 + (size_t)bb * HWs * 128;
  const f16* a1 = act1 + (size_t)bb * HWs * 128;
  f16* Qs = buf;
  f16* Ks = buf + 64 * 72;
  const int lrow = l & 15, lk = (l >> 4) * 8;

  // stage Q (act2 ch 64..127)
#pragma unroll
  for (int it = 0; it < 2; it++) {
    int t = it * 256 + tid;
    int q = t >> 3, seg = t & 7;
    int gp = (y0 + (q >> 3)) * WW + x0 + (q & 7);
    *(f16x8*)&Qs[q * 72 + seg * 8] = *(const f16x8*)&a2[(size_t)gp * 128 + 64 + seg * 8];
  }
  // stage K (act2 ch 0..63), 208 halo rows, zero OOB
  for (int t = tid; t < 1664; t += 256) {
    int kk = t >> 3, seg = t & 7;
    int ky = (kk * 4682) >> 16, kx = kk - 14 * ky;
    int gy = y0 - 3 + ky, gx = x0 - 3 + kx;
    f16x8 v = {(f16)0, (f16)0, (f16)0, (f16)0, (f16)0, (f16)0, (f16)0, (f16)0};
    if (kk < 196 && (unsigned)gy < (unsigned)HH && (unsigned)gx < (unsigned)WW)
      v = *(const f16x8*)&a2[((size_t)(gy * WW + gx)) * 128 + seg * 8];
    *(f16x8*)&Ks[kk * 72 + seg * 8] = v;
  }
  __syncthreads();

  // QK: wave w -> q-rows 16w..16w+15, 13 col-frags, K=64 in 2 steps
  f32x4 sc[13];
#pragma unroll
  for (int nj = 0; nj < 13; nj++) sc[nj] = (f32x4){0.f, 0.f, 0.f, 0.f};
#pragma unroll
  for (int ks = 0; ks < 2; ks++) {
    f16x8 aq = *(const f16x8*)&Qs[(w * 16 + lrow) * 72 + ks * 32 + lk];
#pragma unroll
    for (int nj = 0; nj < 13; nj++) {
      f16x8 bk = *(const f16x8*)&Ks[(nj * 16 + lrow) * 72 + ks * 32 + lk];
      sc[nj] = __builtin_amdgcn_mfma_f32_16x16x32_f16(aq, bk, sc[nj], 0, 0, 0);
    }
  }
  // mask non-window cols (image-OOB stays 0 via zero-staged K = reference semantics)
  const int r0 = w * 16 + (l >> 4) * 4;
#pragma unroll
  for (int nj = 0; nj < 13; nj++) {
    int c = nj * 16 + lrow;
    int ky = (c * 4682) >> 16, kx = c - 14 * ky;
#pragma unroll
    for (int r = 0; r < 4; r++) {
      int qy = (r0 + r) >> 3, qx = (r0 + r) & 7;
      bool valid = ((unsigned)(ky - qy) < 7u) && ((unsigned)(kx - qx) < 7u);
      if (!valid) sc[nj][r] = -1e30f;
    }
  }
  // softmax per q-row
  float mx[4], sm[4], inv[4];
#pragma unroll
  for (int r = 0; r < 4; r++) {
    mx[r] = -1e30f;
#pragma unroll
    for (int nj = 0; nj < 13; nj++) mx[r] = fmaxf(mx[r], sc[nj][r]);
  }
#pragma unroll
  for (int off = 1; off < 16; off <<= 1)
#pragma unroll
    for (int r = 0; r < 4; r++) mx[r] = fmaxf(mx[r], __shfl_xor(mx[r], off));
#pragma unroll
  for (int r = 0; r < 4; r++) sm[r] = 0.f;
#pragma unroll
  for (int nj = 0; nj < 13; nj++)
#pragma unroll
    for (int r = 0; r < 4; r++) {
      float e = __expf(sc[nj][r] - mx[r]);
      sc[nj][r] = e; sm[r] += e;
    }
#pragma unroll
  for (int off = 1; off < 16; off <<= 1)
#pragma unroll
    for (int r = 0; r < 4; r++) sm[r] += __shfl_xor(sm[r], off);
#pragma unroll
  for (int r = 0; r < 4; r++) inv[r] = 1.0f / sm[r];
#pragma unroll
  for (int nj = 0; nj < 13; nj++) {
    int c = nj * 16 + lrow;
    int ky = (c * 4682) >> 16, kx = c - 14 * ky;
#pragma unroll
    for (int r = 0; r < 4; r++) {
      int qy = (r0 + r) >> 3, qx = (r0 + r) & 7;
      int dy = ky - qy, dx = kx - qx;
      if (((unsigned)dy < 7u) && ((unsigned)dx < 7u))
        Ps[(r0 + r) * 52 + dy * 7 + dx] = sc[nj][r] * inv[r];
    }
  }
  __syncthreads();

  // stage V (act1 ch 0..127) into full buf
  f16* Vs = buf;
  for (int t = tid; t < 3328; t += 256) {
    int kk = t >> 4, seg = t & 15;
    int ky = (kk * 4682) >> 16, kx = kk - 14 * ky;
    int gy = y0 - 3 + ky, gx = x0 - 3 + kx;
    f16x8 v = {(f16)0, (f16)0, (f16)0, (f16)0, (f16)0, (f16)0, (f16)0, (f16)0};
    if (kk < 196 && (unsigned)gy < (unsigned)HH && (unsigned)gx < (unsigned)WW)
      v = *(const f16x8*)&a1[((size_t)(gy * WW + gx)) * 128 + seg * 8];
    *(f16x8*)&Vs[kk * 136 + seg * 8] = v;
  }
  __syncthreads();

  // PV: thread = (pixel q = tid>>2, 32-ch chunk), f32 accum
  const int q = tid >> 2;
  const int qy = q >> 3, qx = q & 7;
  const int ch0 = (tid & 3) * 32;
  float acc[32];
#pragma unroll
  for (int i = 0; i < 32; i++) acc[i] = 0.f;
#pragma unroll
  for (int dy = 0; dy < 7; dy++)
#pragma unroll
    for (int dx = 0; dx < 7; dx++) {
      float p = Ps[q * 52 + dy * 7 + dx];
      int kk = (qy + dy) * 14 + qx + dx;
      const f16* vp = &Vs[kk * 136 + ch0];
#pragma unroll
      for (int s = 0; s < 4; s++) {
        f16x8 v = *(const f16x8*)&vp[s * 8];
#pragma unroll
        for (int j = 0; j < 8; j++) acc[s * 8 + j] += (float)v[j] * p;
      }
    }
  __syncthreads();   // all PV reads of Vs complete before ctx overwrite

  // ctx -> LDS (reuse buf)
  f16* ctxs = buf;
#pragma unroll
  for (int s = 0; s < 4; s++) {
    f16x8 o;
#pragma unroll
    for (int j = 0; j < 8; j++) o[j] = (f16)acc[s * 8 + j];
    *(f16x8*)&ctxs[q * 136 + ch0 + s * 8] = o;
  }
  __syncthreads();

  // final projection: wave w -> couts [64w, 64w+64); A = W3 (global/L2), B = ctx^T (LDS)
  f32x4 fac[4][4];
#pragma unroll
  for (int i = 0; i < 4; i++)
#pragma unroll
    for (int j = 0; j < 4; j++) fac[i][j] = (f32x4){0.f, 0.f, 0.f, 0.f};
#pragma unroll
  for (int ks = 0; ks < 4; ks++) {
    f16x8 a3[4], b3[4];
#pragma unroll
    for (int mi = 0; mi < 4; mi++)
      a3[mi] = *(const f16x8*)&W3[(size_t)(w * 64 + mi * 16 + lrow) * 128 + ks * 32 + lk];
#pragma unroll
    for (int nj = 0; nj < 4; nj++)
      b3[nj] = *(const f16x8*)&ctxs[(nj * 16 + lrow) * 136 + ks * 32 + lk];
#pragma unroll
    for (int mi = 0; mi < 4; mi++)
#pragma unroll
      for (int nj = 0; nj < 4; nj++)
        fac[mi][nj] = __builtin_amdgcn_mfma_f32_16x16x32_f16(a3[mi], b3[nj], fac[mi][nj], 0, 0, 0);
  }
#pragma unroll
  for (int mi = 0; mi < 4; mi++)
#pragma unroll
    for (int nj = 0; nj < 4; nj++) {
#pragma unroll
      for (int r = 0; r < 4; r++) {
        int cout = w * 64 + mi * 16 + (l >> 4) * 4 + r;
        int px = nj * 16 + lrow;
        int gp = (y0 + (px >> 3)) * WW + x0 + (px & 7);
        out[((size_t)bb * 256 + cout) * HWs + gp] = fac[mi][nj][r] + st[768 + cout];
      }
    }
}

extern "C" void kernel_launch(void* const* d_in, const int* in_sizes, int n_in,
                              void* d_out, int out_size, void* d_ws, size_t ws_size,
                              hipStream_t stream) {
  (void)in_sizes; (void)n_in; (void)out_size; (void)ws_size;
  const float* x      = (const float*)d_in[0];
  const float* fk_w1  = (const float*)d_in[1];
  const float* fk_b1  = (const float*)d_in[2];
  const float* fk_bn1 = (const float*)d_in[3];
  const float* fk_w2  = (const float*)d_in[4];
  const float* fk_b2  = (const float*)d_in[5];
  const float* fk_bn2 = (const float*)d_in[6];
  const float* fq_w1  = (const float*)d_in[7];
  const float* fq_b1  = (const float*)d_in[8];
  const float* fq_bn1 = (const float*)d_in[9];
  const float* fq_w2  = (const float*)d_in[10];
  const float* fq_b2  = (const float*)d_in[11];
  const float* fq_bn2 = (const float*)d_in[12];
  const float* fv_w   = (const float*)d_in[13];
  const float* fv_b   = (const float*)d_in[14];
  const float* W_w    = (const float*)d_in[15];
  const float* W_b    = (const float*)d_in[16];
  char* wsb = (char*)d_ws;
  float* out = (float*)d_out;

  f16* act1 = (f16*)(wsb + OFF_ACT1);
  f16* act2 = (f16*)(wsb + OFF_ACT2);
  f16* w1   = (f16*)(wsb + OFF_W1);
  f16* w2   = (f16*)(wsb + OFF_W2);
  f16* w3   = (f16*)(wsb + OFF_W3);
  float* st = (float*)(wsb + OFF_ST);

  prep_kernel<<<dim3(419), dim3(256), 0, stream>>>(
      fk_w1, fk_b1, fk_bn1, fk_w2, fk_b2, fk_bn2,
      fq_w1, fq_b1, fq_bn1, fq_w2, fq_b2, fq_bn2, fv_w, fv_b, W_w, W_b, wsb);

  conv12<<<dim3(288, 2), dim3(256), 0, stream>>>(x, w1, w2, act1, act2, st);

  attn_final<<<dim3(12, 12, 2), dim3(256), 0, stream>>>(act1, act2, w3, st, out);
}